// Round 1
// baseline (240.738 us; speedup 1.0000x reference)
//
#include <hip/hip_runtime.h>
#include <math.h>

#define VOCABN 100000
#define EMBD 300
#define HID 128
#define NQ 32
#define NTOP 10

#define RB 64
#define KC 50
#define ABLK 400
#define NA_BLOCKS 250   // 250*400 = 100000 exactly

// ---------------- query context + scorer bias ----------------
__global__ void k_qctx(const int* __restrict__ qterms,
                       const float* __restrict__ emb,
                       const float* __restrict__ sW1,
                       const float* __restrict__ sb1,
                       float* __restrict__ qctx, float* __restrict__ qcb) {
    __shared__ float qc[EMBD];
    int t = threadIdx.x;
    if (t < EMBD) {
        float s = 0.f;
        for (int i = 0; i < NQ; ++i) s += emb[(long)qterms[i] * EMBD + t];
        s *= (1.0f / NQ);
        qc[t] = s;
        qctx[t] = s;
    }
    __syncthreads();
    if (t < HID) {
        float a = sb1[t];
        for (int k = 0; k < EMBD; ++k) a += qc[k] * sW1[(EMBD + k) * HID + t];
        qcb[t] = a;
    }
}

// ---------------- histogram of feedback term ids ----------------
__global__ void k_hist(const int* __restrict__ ids, int* __restrict__ counts, int n) {
    int i = blockIdx.x * blockDim.x + threadIdx.x;
    if (i < n) atomicAdd(&counts[ids[i]], 1);
}

// ---------------- per-vocab score * count ----------------
// weights[v] = count[v] * sigmoid( W2 . relu( emb[v] . W1a + qcb ) + b2 )
__global__ __launch_bounds__(256) void k_score(const float* __restrict__ emb,
                                               const float* __restrict__ sW1,
                                               const float* __restrict__ sW2,
                                               const float* __restrict__ sb2,
                                               const float* __restrict__ qcb,
                                               const int* __restrict__ counts,
                                               float* __restrict__ weights) {
    __shared__ float Wt[KC][HID];      // 25.6 KB
    __shared__ float Et[RB][KC + 2];   // 13.3 KB, +2 pad breaks bank aliasing
    __shared__ float qcb_s[HID];

    int tid = threadIdx.x;
    int v0 = blockIdx.x * RB;
    if (tid < HID) qcb_s[tid] = qcb[tid];

    float acc[4][8];
#pragma unroll
    for (int r = 0; r < 4; ++r)
#pragma unroll
        for (int c = 0; c < 8; ++c) acc[r][c] = 0.f;

    const int cc = tid & 15;   // col group: cols cc*4..cc*4+3 and 64+cc*4..+3
    const int cr = tid >> 4;   // row group: rows cr*4..cr*4+3

    for (int kc = 0; kc < EMBD; kc += KC) {
        // stage W chunk [KC][HID]
        for (int i = tid; i < KC * HID; i += 256) {
            int kk = i >> 7, c = i & 127;
            Wt[kk][c] = sW1[(kc + kk) * HID + c];
        }
        // stage E chunk [RB][KC]
        for (int i = tid; i < RB * KC; i += 256) {
            int r = i / KC, k = i - r * KC;
            int row = v0 + r;
            if (row >= VOCABN) row = VOCABN - 1;
            Et[r][k] = emb[(long)row * EMBD + kc + k];
        }
        __syncthreads();

#pragma unroll 2
        for (int k = 0; k < KC; ++k) {
            float e0 = Et[cr * 4 + 0][k];
            float e1 = Et[cr * 4 + 1][k];
            float e2 = Et[cr * 4 + 2][k];
            float e3 = Et[cr * 4 + 3][k];
            const float4 w0 = *(const float4*)&Wt[k][cc * 4];
            const float4 w1 = *(const float4*)&Wt[k][64 + cc * 4];
            acc[0][0] += e0 * w0.x; acc[0][1] += e0 * w0.y; acc[0][2] += e0 * w0.z; acc[0][3] += e0 * w0.w;
            acc[0][4] += e0 * w1.x; acc[0][5] += e0 * w1.y; acc[0][6] += e0 * w1.z; acc[0][7] += e0 * w1.w;
            acc[1][0] += e1 * w0.x; acc[1][1] += e1 * w0.y; acc[1][2] += e1 * w0.z; acc[1][3] += e1 * w0.w;
            acc[1][4] += e1 * w1.x; acc[1][5] += e1 * w1.y; acc[1][6] += e1 * w1.z; acc[1][7] += e1 * w1.w;
            acc[2][0] += e2 * w0.x; acc[2][1] += e2 * w0.y; acc[2][2] += e2 * w0.z; acc[2][3] += e2 * w0.w;
            acc[2][4] += e2 * w1.x; acc[2][5] += e2 * w1.y; acc[2][6] += e2 * w1.z; acc[2][7] += e2 * w1.w;
            acc[3][0] += e3 * w0.x; acc[3][1] += e3 * w0.y; acc[3][2] += e3 * w0.z; acc[3][3] += e3 * w0.w;
            acc[3][4] += e3 * w1.x; acc[3][5] += e3 * w1.y; acc[3][6] += e3 * w1.z; acc[3][7] += e3 * w1.w;
        }
        __syncthreads();
    }

    // epilogue: relu + dot with W2 + sigmoid + count scaling
    float w2v[8];
#pragma unroll
    for (int i = 0; i < 4; ++i) {
        w2v[i] = sW2[cc * 4 + i];
        w2v[4 + i] = sW2[64 + cc * 4 + i];
    }
    float b2 = sb2[0];
#pragma unroll
    for (int r = 0; r < 4; ++r) {
        float p = 0.f;
#pragma unroll
        for (int i = 0; i < 4; ++i) {
            float h0 = acc[r][i] + qcb_s[cc * 4 + i];       h0 = h0 > 0.f ? h0 : 0.f;
            float h1 = acc[r][4 + i] + qcb_s[64 + cc * 4 + i]; h1 = h1 > 0.f ? h1 : 0.f;
            p += h0 * w2v[i] + h1 * w2v[4 + i];
        }
        // reduce across the 16 cc-lanes (contiguous 16-lane groups)
        for (int m = 1; m < 16; m <<= 1) p += __shfl_xor(p, m);
        if (cc == 0) {
            int v = v0 + cr * 4 + r;
            if (v < VOCABN) {
                float z = p + b2;
                float s = 1.0f / (1.0f + expf(-z));
                weights[v] = (float)counts[v] * s;
            }
        }
    }
}

// ---------------- top-k phase A: per-block top-10 ----------------
__global__ void k_topA(const float* __restrict__ weights,
                       float* __restrict__ tw, int* __restrict__ tidout) {
    __shared__ float wv[ABLK];
    __shared__ float bw[256];
    __shared__ int bi[256];
    int t = threadIdx.x;
    int base = blockIdx.x * ABLK;
    for (int i = t; i < ABLK; i += 256) wv[i] = weights[base + i];
    __syncthreads();
    for (int round = 0; round < NTOP; ++round) {
        float best = -1.f; int besti = ABLK;
        for (int i = t; i < ABLK; i += 256) {
            float w = wv[i];
            if (w > best || (w == best && i < besti)) { best = w; besti = i; }
        }
        bw[t] = best; bi[t] = besti;
        __syncthreads();
        for (int s = 128; s > 0; s >>= 1) {
            if (t < s) {
                float w2 = bw[t + s]; int i2 = bi[t + s];
                if (w2 > bw[t] || (w2 == bw[t] && i2 < bi[t])) { bw[t] = w2; bi[t] = i2; }
            }
            __syncthreads();
        }
        if (t == 0) {
            tw[blockIdx.x * NTOP + round] = bw[0];
            tidout[blockIdx.x * NTOP + round] = base + bi[0];
            wv[bi[0]] = -1.f;
        }
        __syncthreads();
    }
}

// ---------------- top-k phase B + final MLP ----------------
__global__ __launch_bounds__(1024) void k_final(const float* __restrict__ tw,
                                                const int* __restrict__ tids,
                                                const float* __restrict__ qctx,
                                                const float* __restrict__ emb,
                                                const float* __restrict__ eW1,
                                                const float* __restrict__ eb1,
                                                const float* __restrict__ eW2,
                                                const float* __restrict__ eb2,
                                                float* __restrict__ out) {
    const int NA = NA_BLOCKS * NTOP;  // 2500
    __shared__ float wv[NA];
    __shared__ int wid[NA];
    __shared__ float bw[1024];
    __shared__ int bid[1024];
    __shared__ int bslot[1024];
    __shared__ int top_id[NTOP];
    __shared__ float top_w[NTOP];
    __shared__ float qc[EMBD], em[EMBD], hbuf[HID];

    int t = threadIdx.x;
    for (int i = t; i < NA; i += 1024) { wv[i] = tw[i]; wid[i] = tids[i]; }
    __syncthreads();

    for (int round = 0; round < NTOP; ++round) {
        float best = -1.f; int besti = 0x7fffffff; int bests = 0;
        for (int i = t; i < NA; i += 1024) {
            float w = wv[i]; int id = wid[i];
            if (w > best || (w == best && id < besti)) { best = w; besti = id; bests = i; }
        }
        bw[t] = best; bid[t] = besti; bslot[t] = bests;
        __syncthreads();
        for (int s = 512; s > 0; s >>= 1) {
            if (t < s) {
                float w2 = bw[t + s];
                if (w2 > bw[t] || (w2 == bw[t] && bid[t + s] < bid[t])) {
                    bw[t] = w2; bid[t] = bid[t + s]; bslot[t] = bslot[t + s];
                }
            }
            __syncthreads();
        }
        if (t == 0) {
            top_id[round] = bid[0];
            top_w[round] = bw[0];
            wv[bslot[0]] = -1.f;
        }
        __syncthreads();
    }

    // outputs: ids (as float) and weights
    if (t < NTOP) {
        out[EMBD + t] = (float)top_id[t];
        out[EMBD + NTOP + t] = top_w[t];
    }

    // exp_mean + qctx into LDS
    if (t < EMBD) {
        float s = 0.f;
        for (int i = 0; i < NTOP; ++i) s += emb[(long)top_id[i] * EMBD + t];
        em[t] = s * (1.0f / NTOP);
        qc[t] = qctx[t];
    }
    __syncthreads();

    // h = relu(feat . eW1 + eb1), feat = [qc, em, qc*em]
    if (t < HID) {
        float a = eb1[t];
        for (int k = 0; k < EMBD; ++k)       a += qc[k] * eW1[k * HID + t];
        for (int k = 0; k < EMBD; ++k)       a += em[k] * eW1[(EMBD + k) * HID + t];
        for (int k = 0; k < EMBD; ++k)       a += qc[k] * em[k] * eW1[(2 * EMBD + k) * HID + t];
        hbuf[t] = a > 0.f ? a : 0.f;
    }
    __syncthreads();

    // out = h . eW2 + eb2
    if (t < EMBD) {
        float a = eb2[t];
        for (int j = 0; j < HID; ++j) a += hbuf[j] * eW2[j * EMBD + t];
        out[t] = a;
    }
}

extern "C" void kernel_launch(void* const* d_in, const int* in_sizes, int n_in,
                              void* d_out, int out_size, void* d_ws, size_t ws_size,
                              hipStream_t stream) {
    const int* qterms  = (const int*)d_in[0];
    const int* fdocs   = (const int*)d_in[1];
    // d_in[2] = n_terms (fixed at 10)
    const float* emb   = (const float*)d_in[3];
    const float* sW1   = (const float*)d_in[4];
    const float* sb1   = (const float*)d_in[5];
    const float* sW2   = (const float*)d_in[6];
    const float* sb2   = (const float*)d_in[7];
    const float* eW1   = (const float*)d_in[8];
    const float* eb1   = (const float*)d_in[9];
    const float* eW2   = (const float*)d_in[10];
    const float* eb2   = (const float*)d_in[11];
    float* out = (float*)d_out;

    char* ws = (char*)d_ws;
    int*   counts  = (int*)(ws + 0);            // 400000 B
    float* weights = (float*)(ws + 400000);     // 400000 B
    float* qctx    = (float*)(ws + 800000);     // 1200 B
    float* qcb     = (float*)(ws + 801200);     // 512 B
    float* taw     = (float*)(ws + 801712);     // 10000 B
    int*   tai     = (int*)(ws + 811712);       // 10000 B

    int nflat = in_sizes[1];

    hipMemsetAsync(counts, 0, VOCABN * sizeof(int), stream);
    k_qctx<<<1, 320, 0, stream>>>(qterms, emb, sW1, sb1, qctx, qcb);
    k_hist<<<(nflat + 255) / 256, 256, 0, stream>>>(fdocs, counts, nflat);
    k_score<<<(VOCABN + RB - 1) / RB, 256, 0, stream>>>(emb, sW1, sW2, sb2, qcb, counts, weights);
    k_topA<<<NA_BLOCKS, 256, 0, stream>>>(weights, taw, tai);
    k_final<<<1, 1024, 0, stream>>>(taw, tai, qctx, emb, eW1, eb1, eW2, eb2, out);
}

// Round 2
// 229.316 us; speedup vs baseline: 1.0498x; 1.0498x over previous
//
#include <hip/hip_runtime.h>
#include <math.h>

#define VOCABN 100000
#define EMBD 300
#define HID 128
#define NQ 32
#define NTOP 10

// k_score tiling
#define SC_ROWS 256       // rows per block
#define SC_KC 20          // K chunk (300 = 15 * 20)
#define SC_EST 24         // Et row stride (floats): 24*4B, 16B-aligned, 2-way banks only

// top-k phase A
#define NB_A 125
#define ABLK 800          // 125*800 = 100000 exactly

// ---------------- query context + scorer bias ----------------
__global__ void k_qctx(const int* __restrict__ qterms,
                       const float* __restrict__ emb,
                       const float* __restrict__ sW1,
                       const float* __restrict__ sb1,
                       float* __restrict__ qctx, float* __restrict__ qcb) {
    __shared__ float qc[EMBD];
    int t = threadIdx.x;
    if (t < EMBD) {
        float s = 0.f;
        for (int i = 0; i < NQ; ++i) s += emb[(long)qterms[i] * EMBD + t];
        s *= (1.0f / NQ);
        qc[t] = s;
        qctx[t] = s;
    }
    __syncthreads();
    if (t < HID) {
        float a = sb1[t];
        for (int k = 0; k < EMBD; ++k) a += qc[k] * sW1[(EMBD + k) * HID + t];
        qcb[t] = a;
    }
}

// ---------------- histogram of feedback term ids ----------------
__global__ void k_hist(const int* __restrict__ ids, int* __restrict__ counts, int n) {
    int i = blockIdx.x * blockDim.x + threadIdx.x;
    if (i < n) atomicAdd(&counts[ids[i]], 1);
}

// ---------------- compact ids with count > 0 ----------------
__global__ void k_compact(const int* __restrict__ counts, int* __restrict__ cand,
                          int* __restrict__ ncand) {
    int i = blockIdx.x * blockDim.x + threadIdx.x;
    if (i < VOCABN && counts[i] > 0) {
        int pos = atomicAdd(ncand, 1);
        cand[pos] = i;
    }
}

// ---------------- per-candidate score * count ----------------
// weights[v] = count[v] * sigmoid( W2 . relu( emb[v] . W1a + qcb ) + b2 )
// 256 threads; thread (cc=tid&7, cr=tid>>3) computes rows {cr+32r} x cols {cc*4+q*32+i}
__global__ __launch_bounds__(256) void k_score(const float* __restrict__ emb,
                                               const float* __restrict__ sW1,
                                               const float* __restrict__ sW2,
                                               const float* __restrict__ sb2,
                                               const float* __restrict__ qcb,
                                               const int* __restrict__ counts,
                                               const int* __restrict__ cand,
                                               const int* __restrict__ ncand_p,
                                               float* __restrict__ weights) {
    __shared__ float Wt[SC_KC][HID];        // 10.24 KB
    __shared__ float Et[SC_ROWS][SC_EST];   // 24.58 KB
    __shared__ int   cid[SC_ROWS];
    __shared__ float qcb_s[HID];
    __shared__ float w2_s[HID];

    const int tid = threadIdx.x;
    const int ncand = ncand_p ? *ncand_p : VOCABN;
    const int base = blockIdx.x * SC_ROWS;
    if (base >= ncand) return;

    if (tid < HID) { qcb_s[tid] = qcb[tid]; w2_s[tid] = sW2[tid]; }
    {
        int i = base + tid;
        int ci = i < ncand ? i : (ncand - 1);
        cid[tid] = cand ? cand[ci] : ci;
    }

    float acc[8][16];
#pragma unroll
    for (int r = 0; r < 8; ++r)
#pragma unroll
        for (int c = 0; c < 16; ++c) acc[r][c] = 0.f;

    const int cc = tid & 7;    // 8 col groups
    const int cr = tid >> 3;   // 32 row groups

    __syncthreads();   // cid ready before staging

    for (int kc = 0; kc < EMBD; kc += SC_KC) {
        if (kc) __syncthreads();   // previous chunk's readers done
        // stage W chunk [SC_KC][128]: 640 float4
        for (int s = tid; s < (SC_KC * HID) / 4; s += 256) {
            int k = s >> 5;
            int c4 = (s & 31) << 2;
            *(float4*)&Wt[k][c4] = *(const float4*)&sW1[(kc + k) * HID + c4];
        }
        // stage E chunk [256 rows][20 floats]: 1280 float4
        for (int s = tid; s < SC_ROWS * (SC_KC / 4); s += 256) {
            int r = s / (SC_KC / 4);
            int c4 = (s - r * (SC_KC / 4)) * 4;
            *(float4*)&Et[r][c4] = *(const float4*)&emb[(long)cid[r] * EMBD + kc + c4];
        }
        __syncthreads();

        for (int k4 = 0; k4 < SC_KC; k4 += 4) {
            float e_s[8][4];
#pragma unroll
            for (int r = 0; r < 8; ++r) {
                float4 ev = *(const float4*)&Et[cr + 32 * r][k4];
                e_s[r][0] = ev.x; e_s[r][1] = ev.y; e_s[r][2] = ev.z; e_s[r][3] = ev.w;
            }
#pragma unroll
            for (int kk = 0; kk < 4; ++kk) {
                const float4 w0 = *(const float4*)&Wt[k4 + kk][cc * 4];
                const float4 w1 = *(const float4*)&Wt[k4 + kk][cc * 4 + 32];
                const float4 w2 = *(const float4*)&Wt[k4 + kk][cc * 4 + 64];
                const float4 w3 = *(const float4*)&Wt[k4 + kk][cc * 4 + 96];
#pragma unroll
                for (int r = 0; r < 8; ++r) {
                    float e = e_s[r][kk];
                    acc[r][0]  += e * w0.x; acc[r][1]  += e * w0.y;
                    acc[r][2]  += e * w0.z; acc[r][3]  += e * w0.w;
                    acc[r][4]  += e * w1.x; acc[r][5]  += e * w1.y;
                    acc[r][6]  += e * w1.z; acc[r][7]  += e * w1.w;
                    acc[r][8]  += e * w2.x; acc[r][9]  += e * w2.y;
                    acc[r][10] += e * w2.z; acc[r][11] += e * w2.w;
                    acc[r][12] += e * w3.x; acc[r][13] += e * w3.y;
                    acc[r][14] += e * w3.z; acc[r][15] += e * w3.w;
                }
            }
        }
    }

    // epilogue: relu + dot W2 + 8-lane reduce + sigmoid * count
    const float b2 = sb2[0];
#pragma unroll
    for (int r = 0; r < 8; ++r) {
        float p = 0.f;
#pragma unroll
        for (int q = 0; q < 4; ++q)
#pragma unroll
            for (int i = 0; i < 4; ++i) {
                int col = cc * 4 + q * 32 + i;
                float h = acc[r][q * 4 + i] + qcb_s[col];
                h = h > 0.f ? h : 0.f;
                p += h * w2_s[col];
            }
        p += __shfl_xor(p, 1);
        p += __shfl_xor(p, 2);
        p += __shfl_xor(p, 4);
        if (cc == 0) {
            int row = cr + 32 * r;
            if (base + row < ncand) {
                int v = cid[row];
                float s = 1.0f / (1.0f + expf(-(p + b2)));
                weights[v] = (float)counts[v] * s;
            }
        }
    }
}

// ---------------- top-k helpers ----------------
__device__ __forceinline__ bool tbetter(float w1, int i1, float w2, int i2) {
    return w1 > w2 || (w1 == w2 && i1 < i2);
}

// tree-merge 256 sorted-desc NTOP lists held in LDS down to list 0
__device__ __forceinline__ void topk_merge256(float* mw, int* mid, int t) {
    for (int s = 128; s > 0; s >>= 1) {
        __syncthreads();
        if (t < s) {
            const int ta = t * NTOP, tb = (t + s) * NTOP;
            float ow[NTOP]; int oid[NTOP];
            int i = 0, j = 0;
#pragma unroll
            for (int n = 0; n < NTOP; ++n) {
                float wa = mw[ta + i]; int ia = mid[ta + i];
                float wb = mw[tb + j]; int ib = mid[tb + j];
                if (tbetter(wa, ia, wb, ib)) { ow[n] = wa; oid[n] = ia; ++i; }
                else                         { ow[n] = wb; oid[n] = ib; ++j; }
            }
#pragma unroll
            for (int n = 0; n < NTOP; ++n) { mw[ta + n] = ow[n]; mid[ta + n] = oid[n]; }
        }
    }
    __syncthreads();
}

__device__ __forceinline__ void lds_insert(float* mw, int* mid, int t, float w, int id) {
    const int b = t * NTOP;
    if (!tbetter(w, id, mw[b + NTOP - 1], mid[b + NTOP - 1])) return;
    int p = NTOP - 1;
    while (p > 0 && tbetter(w, id, mw[b + p - 1], mid[b + p - 1])) {
        mw[b + p] = mw[b + p - 1]; mid[b + p] = mid[b + p - 1]; --p;
    }
    mw[b + p] = w; mid[b + p] = id;
}

// ---------------- top-k phase A: per-block top-10, single pass ----------------
__global__ __launch_bounds__(256) void k_topA(const float* __restrict__ weights,
                                              float* __restrict__ tw, int* __restrict__ tido) {
    __shared__ float mw[256 * NTOP];
    __shared__ int   mid[256 * NTOP];
    int t = threadIdx.x;
#pragma unroll
    for (int n = 0; n < NTOP; ++n) { mw[t * NTOP + n] = -1.f; mid[t * NTOP + n] = 0x7fffffff; }
    int base = blockIdx.x * ABLK;
    for (int i = t; i < ABLK; i += 256) {
        int id = base + i;
        lds_insert(mw, mid, t, weights[id], id);
    }
    topk_merge256(mw, mid, t);
    if (t < NTOP) {
        tw[blockIdx.x * NTOP + t] = mw[t];
        tido[blockIdx.x * NTOP + t] = mid[t];
    }
}

// ---------------- top-k phase B + final MLP ----------------
__global__ __launch_bounds__(256) void k_final(const float* __restrict__ tw,
                                               const int* __restrict__ tids,
                                               const float* __restrict__ qctx,
                                               const float* __restrict__ emb,
                                               const float* __restrict__ eW1,
                                               const float* __restrict__ eb1,
                                               const float* __restrict__ eW2,
                                               const float* __restrict__ eb2,
                                               float* __restrict__ out) {
    __shared__ float mw[256 * NTOP];
    __shared__ int   mid[256 * NTOP];
    __shared__ int   top_id[NTOP];
    __shared__ float qc[EMBD], em[EMBD], hbuf[HID];
    int t = threadIdx.x;
#pragma unroll
    for (int n = 0; n < NTOP; ++n) { mw[t * NTOP + n] = -1.f; mid[t * NTOP + n] = 0x7fffffff; }
    for (int i = t; i < NB_A * NTOP; i += 256)
        lds_insert(mw, mid, t, tw[i], tids[i]);
    topk_merge256(mw, mid, t);

    if (t < NTOP) {
        top_id[t] = mid[t];
        out[EMBD + t] = (float)mid[t];
        out[EMBD + NTOP + t] = mw[t];
    }
    __syncthreads();

    // exp_mean + qctx
    for (int i = t; i < EMBD; i += 256) {
        float s = 0.f;
        for (int n = 0; n < NTOP; ++n) s += emb[(long)top_id[n] * EMBD + i];
        em[i] = s * (1.0f / NTOP);
        qc[i] = qctx[i];
    }
    __syncthreads();

    if (t < HID) {
        float a = eb1[t];
        for (int k = 0; k < EMBD; ++k) a += qc[k] * eW1[k * HID + t];
        for (int k = 0; k < EMBD; ++k) a += em[k] * eW1[(EMBD + k) * HID + t];
        for (int k = 0; k < EMBD; ++k) a += qc[k] * em[k] * eW1[(2 * EMBD + k) * HID + t];
        hbuf[t] = a > 0.f ? a : 0.f;
    }
    __syncthreads();

    for (int i = t; i < EMBD; i += 256) {
        float a = eb2[i];
        for (int j = 0; j < HID; ++j) a += hbuf[j] * eW2[j * EMBD + i];
        out[i] = a;
    }
}

extern "C" void kernel_launch(void* const* d_in, const int* in_sizes, int n_in,
                              void* d_out, int out_size, void* d_ws, size_t ws_size,
                              hipStream_t stream) {
    const int* qterms  = (const int*)d_in[0];
    const int* fdocs   = (const int*)d_in[1];
    const float* emb   = (const float*)d_in[3];
    const float* sW1   = (const float*)d_in[4];
    const float* sb1   = (const float*)d_in[5];
    const float* sW2   = (const float*)d_in[6];
    const float* sb2   = (const float*)d_in[7];
    const float* eW1   = (const float*)d_in[8];
    const float* eb1   = (const float*)d_in[9];
    const float* eW2   = (const float*)d_in[10];
    const float* eb2   = (const float*)d_in[11];
    float* out = (float*)d_out;

    char* ws = (char*)d_ws;
    int*   counts  = (int*)(ws + 0);              // 400000
    float* weights = (float*)(ws + 400000);       // 400000
    float* qctx    = (float*)(ws + 800000);       // 1200
    float* qcb     = (float*)(ws + 801216);       // 512
    float* taw     = (float*)(ws + 801728);       // 5000
    int*   tai     = (int*)(ws + 806784);         // 5000
    int*   ncand   = (int*)(ws + 811776);         // 4
    int*   cand    = (int*)(ws + 811840);         // 400000 (optional)
    const size_t NEED_COMPACT = 1211840;
    const bool use_compact = (ws_size >= NEED_COMPACT);

    int nflat = in_sizes[1];

    // zero counts + weights + ncand in one shot
    hipMemsetAsync(ws, 0, 811780, stream);
    k_qctx<<<1, 320, 0, stream>>>(qterms, emb, sW1, sb1, qctx, qcb);
    k_hist<<<(nflat + 255) / 256, 256, 0, stream>>>(fdocs, counts, nflat);
    if (use_compact) {
        k_compact<<<(VOCABN + 255) / 256, 256, 0, stream>>>(counts, cand, ncand);
        k_score<<<(VOCABN + SC_ROWS - 1) / SC_ROWS, 256, 0, stream>>>(
            emb, sW1, sW2, sb2, qcb, counts, cand, ncand, weights);
    } else {
        k_score<<<(VOCABN + SC_ROWS - 1) / SC_ROWS, 256, 0, stream>>>(
            emb, sW1, sW2, sb2, qcb, counts, (const int*)nullptr, (const int*)nullptr, weights);
    }
    k_topA<<<NB_A, 256, 0, stream>>>(weights, taw, tai);
    k_final<<<1, 256, 0, stream>>>(taw, tai, qctx, emb, eW1, eb1, eW2, eb2, out);
}

// Round 3
// 186.318 us; speedup vs baseline: 1.2921x; 1.2308x over previous
//
#include <hip/hip_runtime.h>
#include <math.h>

#define VOCABN 100000
#define EMBD 300
#define HID 128
#define NQ 32
#define NTOP 10

// k_score tiling: 64 rows/block, 256 threads, per-thread 4 rows x 8 cols
#define SC_ROWS 64
#define SC_KC 20
#define SC_EST 24
#define SC_NBLK ((VOCABN + SC_ROWS - 1) / SC_ROWS)   // 1563

// ---------------- fused histogram + query-context ----------------
__global__ __launch_bounds__(256) void k_pre(const int* __restrict__ qterms,
                                             const int* __restrict__ fdocs, int nflat, int hblocks,
                                             const float* __restrict__ emb,
                                             const float* __restrict__ sW1,
                                             const float* __restrict__ sb1,
                                             int* __restrict__ counts,
                                             float* __restrict__ qctx, float* __restrict__ qcb) {
    int t = threadIdx.x;
    if ((int)blockIdx.x < hblocks) {
        int i = blockIdx.x * 256 + t;
        if (i < nflat) atomicAdd(&counts[fdocs[i]], 1);
        return;
    }
    // last block: query context + scorer bias
    __shared__ int qid[NQ];
    __shared__ float qc[EMBD];
    if (t < NQ) qid[t] = qterms[t];
    __syncthreads();
    for (int i = t; i < EMBD; i += 256) {
        float s = 0.f;
        for (int q = 0; q < NQ; ++q) s += emb[(long)qid[q] * EMBD + i];
        s *= (1.0f / NQ);
        qc[i] = s;
        qctx[i] = s;
    }
    __syncthreads();
    if (t < HID) {
        float a = sb1[t];
        for (int k = 0; k < EMBD; ++k) a += qc[k] * sW1[(long)(EMBD + k) * HID + t];
        qcb[t] = a;
    }
}

// ---------------- compact ids with count > 0 ----------------
__global__ void k_compact(const int* __restrict__ counts, int* __restrict__ cand,
                          int* __restrict__ ccnt, int* __restrict__ ncand) {
    int i = blockIdx.x * blockDim.x + threadIdx.x;
    if (i < VOCABN) {
        int c = counts[i];
        if (c > 0) { int p = atomicAdd(ncand, 1); cand[p] = i; ccnt[p] = c; }
    }
}

// ---------------- score + per-block top-10 ----------------
// weight[v] = count[v] * sigmoid( W2 . relu( emb[v].W1a + qcb ) + b2 )
// thread (cg=tid&15, rg=tid>>4): rows rg+16r (r=0..3), cols cg*4+i and 64+cg*4+i
__global__ __launch_bounds__(256) void k_score(const float* __restrict__ emb,
                                               const float* __restrict__ sW1,
                                               const float* __restrict__ sW2,
                                               const float* __restrict__ sb2,
                                               const float* __restrict__ qcb,
                                               const int* __restrict__ counts,
                                               const int* __restrict__ cand,
                                               const int* __restrict__ ccnt,
                                               const int* __restrict__ ncand_p,
                                               float* __restrict__ taw, int* __restrict__ tai) {
    __shared__ float Wt[SC_KC][HID];        // 10.2 KB
    __shared__ float Et[SC_ROWS][SC_EST];   // 6.1 KB
    __shared__ int   cid[SC_ROWS];
    __shared__ int   ccn[SC_ROWS];
    __shared__ float qcb_s[HID];
    __shared__ float w2_s[HID];
    __shared__ float wv[SC_ROWS];

    const int tid = threadIdx.x;
    const int blk = blockIdx.x;
    const int ncand = ncand_p ? *ncand_p : VOCABN;
    const int base = blk * SC_ROWS;

    if (base >= ncand) {   // uniform per block
        if (tid < NTOP) { taw[blk * NTOP + tid] = -1.f; tai[blk * NTOP + tid] = 0x7fffffff; }
        return;
    }

    if (tid < HID) { qcb_s[tid] = qcb[tid]; w2_s[tid] = sW2[tid]; }
    if (tid < SC_ROWS) {
        int i = base + tid;
        int ci = i < ncand ? i : ncand - 1;
        if (cand) { cid[tid] = cand[ci]; ccn[tid] = ccnt[ci]; }
        else      { cid[tid] = ci;       ccn[tid] = counts[ci]; }
    }

    float acc[4][8];
#pragma unroll
    for (int r = 0; r < 4; ++r)
#pragma unroll
        for (int c = 0; c < 8; ++c) acc[r][c] = 0.f;

    const int cg = tid & 15;
    const int rg = tid >> 4;

    __syncthreads();

    for (int kc = 0; kc < EMBD; kc += SC_KC) {
        if (kc) __syncthreads();
        // stage W chunk [20][128] = 640 float4
        for (int s = tid; s < (SC_KC * HID) / 4; s += 256) {
            int k = s >> 5, c4 = (s & 31) << 2;
            *(float4*)&Wt[k][c4] = *(const float4*)&sW1[(long)(kc + k) * HID + c4];
        }
        // stage E chunk [64][20] = 320 float4
        for (int s = tid; s < SC_ROWS * (SC_KC / 4); s += 256) {
            int r = s / 5, c4 = (s - r * 5) * 4;
            *(float4*)&Et[r][c4] = *(const float4*)&emb[(long)cid[r] * EMBD + kc + c4];
        }
        __syncthreads();

        for (int k4 = 0; k4 < SC_KC; k4 += 4) {
            float4 ev0 = *(const float4*)&Et[rg     ][k4];
            float4 ev1 = *(const float4*)&Et[rg + 16][k4];
            float4 ev2 = *(const float4*)&Et[rg + 32][k4];
            float4 ev3 = *(const float4*)&Et[rg + 48][k4];
            float e[4][4];
            e[0][0]=ev0.x; e[0][1]=ev0.y; e[0][2]=ev0.z; e[0][3]=ev0.w;
            e[1][0]=ev1.x; e[1][1]=ev1.y; e[1][2]=ev1.z; e[1][3]=ev1.w;
            e[2][0]=ev2.x; e[2][1]=ev2.y; e[2][2]=ev2.z; e[2][3]=ev2.w;
            e[3][0]=ev3.x; e[3][1]=ev3.y; e[3][2]=ev3.z; e[3][3]=ev3.w;
#pragma unroll
            for (int kk = 0; kk < 4; ++kk) {
                const float4 w0 = *(const float4*)&Wt[k4 + kk][cg * 4];
                const float4 w1 = *(const float4*)&Wt[k4 + kk][64 + cg * 4];
#pragma unroll
                for (int r = 0; r < 4; ++r) {
                    float ee = e[r][kk];
                    acc[r][0] += ee * w0.x; acc[r][1] += ee * w0.y;
                    acc[r][2] += ee * w0.z; acc[r][3] += ee * w0.w;
                    acc[r][4] += ee * w1.x; acc[r][5] += ee * w1.y;
                    acc[r][6] += ee * w1.z; acc[r][7] += ee * w1.w;
                }
            }
        }
    }

    // epilogue: relu + W2 dot + 16-lane reduce + sigmoid*count
    const float b2 = sb2[0];
#pragma unroll
    for (int r = 0; r < 4; ++r) {
        float p = 0.f;
#pragma unroll
        for (int i = 0; i < 4; ++i) {
            float h0 = acc[r][i]     + qcb_s[cg * 4 + i];
            float h1 = acc[r][4 + i] + qcb_s[64 + cg * 4 + i];
            h0 = fmaxf(h0, 0.f); h1 = fmaxf(h1, 0.f);
            p += h0 * w2_s[cg * 4 + i] + h1 * w2_s[64 + cg * 4 + i];
        }
        p += __shfl_xor(p, 1); p += __shfl_xor(p, 2);
        p += __shfl_xor(p, 4); p += __shfl_xor(p, 8);
        if (cg == 0) {
            int row = rg + 16 * r;
            float wgt = -1.f;
            if (base + row < ncand)
                wgt = (float)ccn[row] / (1.f + expf(-(p + b2)));
            wv[row] = wgt;
        }
    }
    __syncthreads();

    // wave-level top-10 over the 64 row weights
    if (tid < SC_ROWS) {
        float w = wv[tid];
        int id = (base + tid < ncand) ? cid[tid] : 0x7fffffff;
        for (int round = 0; round < NTOP; ++round) {
            float bw = w; int bid = id;
            for (int m = 1; m < 64; m <<= 1) {
                float ow = __shfl_xor(bw, m); int oid = __shfl_xor(bid, m);
                if (ow > bw || (ow == bw && oid < bid)) { bw = ow; bid = oid; }
            }
            if (w == bw && id == bid) w = -2.f;   // knockout winner
            if (tid == round) { taw[blk * NTOP + round] = bw; tai[blk * NTOP + round] = bid; }
        }
    }
}

// ---------------- top-k helpers ----------------
__device__ __forceinline__ bool tbetter(float w1, int i1, float w2, int i2) {
    return w1 > w2 || (w1 == w2 && i1 < i2);
}

__device__ __forceinline__ void lds_insert(float* mw, int* mid, int t, float w, int id) {
    const int b = t * NTOP;
    if (!tbetter(w, id, mw[b + NTOP - 1], mid[b + NTOP - 1])) return;
    int p = NTOP - 1;
    while (p > 0 && tbetter(w, id, mw[b + p - 1], mid[b + p - 1])) {
        mw[b + p] = mw[b + p - 1]; mid[b + p] = mid[b + p - 1]; --p;
    }
    mw[b + p] = w; mid[b + p] = id;
}

// ---------------- final: global top-10 merge + expansion MLP ----------------
__global__ __launch_bounds__(512) void k_final(const float* __restrict__ taw,
                                               const int* __restrict__ tai,
                                               const float* __restrict__ qctx,
                                               const float* __restrict__ emb,
                                               const float* __restrict__ eW1,
                                               const float* __restrict__ eb1,
                                               const float* __restrict__ eW2,
                                               const float* __restrict__ eb2,
                                               float* __restrict__ out) {
    __shared__ float mw[512 * NTOP];   // 20 KB
    __shared__ int   mid[512 * NTOP];  // 20 KB
    __shared__ int   top_id[NTOP];
    __shared__ float qc[EMBD], em[EMBD], hbuf[HID];
    int t = threadIdx.x;
#pragma unroll
    for (int n = 0; n < NTOP; ++n) { mw[t * NTOP + n] = -1.f; mid[t * NTOP + n] = 0x7fffffff; }
    for (int i = t; i < SC_NBLK * NTOP; i += 512)
        lds_insert(mw, mid, t, taw[i], tai[i]);

    for (int s = 256; s > 0; s >>= 1) {
        __syncthreads();
        if (t < s) {
            const int ta = t * NTOP, tb = (t + s) * NTOP;
            float ow[NTOP]; int oid[NTOP];
            int i = 0, j = 0;
#pragma unroll
            for (int n = 0; n < NTOP; ++n) {
                float wa = mw[ta + i]; int ia = mid[ta + i];
                float wb = mw[tb + j]; int ib = mid[tb + j];
                if (tbetter(wa, ia, wb, ib)) { ow[n] = wa; oid[n] = ia; ++i; }
                else                         { ow[n] = wb; oid[n] = ib; ++j; }
            }
#pragma unroll
            for (int n = 0; n < NTOP; ++n) { mw[ta + n] = ow[n]; mid[ta + n] = oid[n]; }
        }
    }
    __syncthreads();

    if (t < NTOP) {
        top_id[t] = mid[t];
        out[EMBD + t] = (float)mid[t];
        out[EMBD + NTOP + t] = mw[t];
    }
    __syncthreads();

    for (int i = t; i < EMBD; i += 512) {
        float s = 0.f;
        for (int n = 0; n < NTOP; ++n) s += emb[(long)top_id[n] * EMBD + i];
        em[i] = s * (1.0f / NTOP);
        qc[i] = qctx[i];
    }
    __syncthreads();

    // h = relu(feat . eW1 + eb1); 4 threads per col split K=300 into 75
    {
        int col = t >> 2, ks = t & 3;
        float a = 0.f;
        int k0 = ks * 75, k1 = k0 + 75;
        for (int k = k0; k < k1; ++k) {
            float q = qc[k], e = em[k];
            a += q * eW1[(long)k * HID + col];
            a += e * eW1[(long)(EMBD + k) * HID + col];
            a += (q * e) * eW1[(long)(2 * EMBD + k) * HID + col];
        }
        a += __shfl_xor(a, 1);
        a += __shfl_xor(a, 2);
        if (ks == 0) hbuf[col] = fmaxf(a + eb1[col], 0.f);
    }
    __syncthreads();

    for (int i = t; i < EMBD; i += 512) {
        float a = eb2[i];
        for (int j = 0; j < HID; ++j) a += hbuf[j] * eW2[(long)j * EMBD + i];
        out[i] = a;
    }
}

extern "C" void kernel_launch(void* const* d_in, const int* in_sizes, int n_in,
                              void* d_out, int out_size, void* d_ws, size_t ws_size,
                              hipStream_t stream) {
    const int* qterms  = (const int*)d_in[0];
    const int* fdocs   = (const int*)d_in[1];
    const float* emb   = (const float*)d_in[3];
    const float* sW1   = (const float*)d_in[4];
    const float* sb1   = (const float*)d_in[5];
    const float* sW2   = (const float*)d_in[6];
    const float* sb2   = (const float*)d_in[7];
    const float* eW1   = (const float*)d_in[8];
    const float* eb1   = (const float*)d_in[9];
    const float* eW2   = (const float*)d_in[10];
    const float* eb2   = (const float*)d_in[11];
    float* out = (float*)d_out;

    char* ws = (char*)d_ws;
    int*   counts = (int*)ws;                       // 400000
    int*   ncand  = (int*)(ws + 400000);            // 4
    float* qctx   = (float*)(ws + 400064);          // 1200
    float* qcb    = (float*)(ws + 401280);          // 512
    const size_t TA_BYTES = (size_t)SC_NBLK * NTOP * 4;  // 62520
    int *cand = nullptr, *ccnt = nullptr;
    size_t off = 401792;
    const bool use_compact = ws_size >= 401792 + 800000 + 2 * TA_BYTES;
    if (use_compact) {
        cand = (int*)(ws + 401792);                 // 400000
        ccnt = (int*)(ws + 801792);                 // 400000
        off = 1201792;
    }
    float* taw = (float*)(ws + off);
    int*   tai = (int*)(ws + off + TA_BYTES);

    int nflat = in_sizes[1];
    int hblocks = (nflat + 255) / 256;

    hipMemsetAsync(ws, 0, 400064, stream);  // counts + ncand
    k_pre<<<hblocks + 1, 256, 0, stream>>>(qterms, fdocs, nflat, hblocks,
                                           emb, sW1, sb1, counts, qctx, qcb);
    if (use_compact) {
        k_compact<<<(VOCABN + 255) / 256, 256, 0, stream>>>(counts, cand, ccnt, ncand);
        k_score<<<SC_NBLK, 256, 0, stream>>>(emb, sW1, sW2, sb2, qcb,
                                             counts, cand, ccnt, ncand, taw, tai);
    } else {
        k_score<<<SC_NBLK, 256, 0, stream>>>(emb, sW1, sW2, sb2, qcb,
                                             counts, nullptr, nullptr, nullptr, taw, tai);
    }
    k_final<<<1, 512, 0, stream>>>(taw, tai, qctx, emb, eW1, eb1, eW2, eb2, out);
}

// Round 4
// 118.646 us; speedup vs baseline: 2.0290x; 1.5704x over previous
//
#include <hip/hip_runtime.h>
#include <math.h>

#define VOCABN 100000
#define EMBD 300
#define HID 128
#define NQ 32
#define NTOP 10

#define KPAD 320            // padded K: 10 chunks of 32
#define NCH 10
#define SC_ROWS 128
#define SC_NBLK ((VOCABN + SC_ROWS - 1) / SC_ROWS)   // 782
#define WSTRIDE 40          // LDS k-stride (bf16) per col: 80B, 16B-aligned, 2-way banks

typedef __attribute__((ext_vector_type(8))) short bf16x8;
typedef __attribute__((ext_vector_type(4))) float f32x4;
typedef __attribute__((ext_vector_type(4))) unsigned int u32x4;

// ---------------- fused: histogram | query-context | W1a transpose+bf16-split ----------------
__global__ __launch_bounds__(256) void k_pre(const int* __restrict__ qterms,
                                             const int* __restrict__ fdocs, int nflat, int hblocks,
                                             const float* __restrict__ emb,
                                             const float* __restrict__ sW1,
                                             int* __restrict__ counts,
                                             float* __restrict__ qctx,
                                             unsigned short* __restrict__ whi,
                                             unsigned short* __restrict__ wlo) {
    int t = threadIdx.x;
    int b = blockIdx.x;
    if (b < hblocks) {                       // histogram
        int i = b * 256 + t;
        if (i < nflat) atomicAdd(&counts[fdocs[i]], 1);
        return;
    }
    if (b == hblocks) {                      // query context
        __shared__ int qid[NQ];
        if (t < NQ) qid[t] = qterms[t];
        __syncthreads();
        for (int i = t; i < EMBD; i += 256) {
            float s = 0.f;
            for (int q = 0; q < NQ; ++q) s += emb[(long)qid[q] * EMBD + i];
            qctx[i] = s * (1.0f / NQ);
        }
        return;
    }
    // W1a (rows 0..299 of sW1) -> transposed, zero-padded, bf16 hi/lo split
    int i = (b - hblocks - 1) * 256 + t;     // over HID*KPAD
    if (i < HID * KPAD) {
        int k = i >> 7, c = i & 127;
        unsigned int hi = 0, lo = 0;
        if (k < EMBD) {
            float f = sW1[(long)k * HID + c];
            unsigned int u = __float_as_uint(f);
            hi = u >> 16;
            float r = __uint_as_float(u & 0xffff0000u);
            lo = __float_as_uint(f - r) >> 16;
        }
        whi[(long)c * KPAD + k] = (unsigned short)hi;
        wlo[(long)c * KPAD + k] = (unsigned short)lo;
    }
}

// ---------------- compact ids with count>0 | qcb = sb1 + qctx . W1b ----------------
__global__ __launch_bounds__(256) void k_compact(const int* __restrict__ counts,
                                                 int* __restrict__ cand, int* __restrict__ ccnt,
                                                 int* __restrict__ ncand, int cblocks,
                                                 const float* __restrict__ qctx,
                                                 const float* __restrict__ sW1,
                                                 const float* __restrict__ sb1,
                                                 float* __restrict__ qcb) {
    int t = threadIdx.x;
    if ((int)blockIdx.x < cblocks) {
        if (cand) {
            int i = blockIdx.x * 256 + t;
            if (i < VOCABN) {
                int c = counts[i];
                if (c > 0) { int p = atomicAdd(ncand, 1); cand[p] = i; ccnt[p] = c; }
            }
        }
        return;
    }
    __shared__ float qc[EMBD];
    for (int i = t; i < EMBD; i += 256) qc[i] = qctx[i];
    __syncthreads();
    int col = t >> 1, half = t & 1;
    float a = 0.f;
    int k0 = half * 150;
    for (int k = k0; k < k0 + 150; ++k)
        a += qc[k] * sW1[(long)(EMBD + k) * HID + col];
    a += __shfl_xor(a, 1);
    if (half == 0) qcb[col] = a + sb1[col];
}

// ---------------- MFMA bf16x3 score + per-block top-10 ----------------
// 512 threads (8 waves). Wave w: rows [16w,16w+16). Cols = all 128.
// acc[t] tiles t=0..7; D layout: row=(lane>>4)*4+i, col=t*16+(lane&15).
__global__ __launch_bounds__(512, 4) void k_score(
        const float* __restrict__ emb,
        const unsigned short* __restrict__ whi,
        const unsigned short* __restrict__ wlo,
        const float* __restrict__ qcb,
        const float* __restrict__ sW2,
        const float* __restrict__ sb2,
        const int* __restrict__ counts,
        const int* __restrict__ cand,
        const int* __restrict__ ccnt,
        const int* __restrict__ ncand_p,
        float* __restrict__ taw, int* __restrict__ tai) {
    __shared__ unsigned short WtH[2][HID * WSTRIDE];   // 20.5 KB
    __shared__ unsigned short WtL[2][HID * WSTRIDE];   // 20.5 KB
    __shared__ float qcb_s[HID], w2_s[HID], wv[SC_ROWS];
    __shared__ int cid[SC_ROWS], ccn[SC_ROWS];

    const int tid = threadIdx.x;
    const int blk = blockIdx.x;
    const int ncand = cand ? *ncand_p : VOCABN;
    const int base = blk * SC_ROWS;

    if (base >= ncand) {
        if (tid < NTOP) { taw[blk * NTOP + tid] = -1.f; tai[blk * NTOP + tid] = 0x7fffffff; }
        return;
    }
    if (tid < HID) { qcb_s[tid] = qcb[tid]; w2_s[tid] = sW2[tid]; }
    if (tid < SC_ROWS) {
        int i = base + tid;
        int ci = i < ncand ? i : ncand - 1;
        if (cand) { cid[tid] = cand[ci]; ccn[tid] = ccnt[ci]; }
        else      { cid[tid] = ci;       ccn[tid] = counts[ci]; }
    }

    const int lane = tid & 63;
    const int wave = tid >> 6;     // 0..7
    const int lrow = lane & 15;
    const int kgrp = lane >> 4;    // 0..3
    const int wcol = tid >> 2;     // staging col 0..127
    const int wseg = tid & 3;      // staging k-seg

    f32x4 acc[8];
#pragma unroll
    for (int t = 0; t < 8; ++t) acc[t] = (f32x4){0.f, 0.f, 0.f, 0.f};

    __syncthreads();   // cid ready

    const long erow = (long)cid[wave * 16 + lrow];
    const long EMAX = (long)VOCABN * EMBD - 8;

    // stage W chunk 0
    {
        u32x4 h = *(const u32x4*)&whi[(long)wcol * KPAD + wseg * 8];
        u32x4 l = *(const u32x4*)&wlo[(long)wcol * KPAD + wseg * 8];
        *(u32x4*)&WtH[0][wcol * WSTRIDE + wseg * 8] = h;
        *(u32x4*)&WtL[0][wcol * WSTRIDE + wseg * 8] = l;
    }
    // E prefetch chunk 0
    long eoff = erow * EMBD + kgrp * 8;
    if (eoff > EMAX) eoff = EMAX;
    f32x4 e0 = *(const f32x4*)&emb[eoff];
    f32x4 e1 = *(const f32x4*)&emb[eoff + 4];
    __syncthreads();

    for (int c = 0; c < NCH; ++c) {
        const int cur = c & 1;
        const bool more = (c + 1 < NCH);
        u32x4 wh, wl; f32x4 n0, n1;
        if (more) {   // prefetch next W chunk (regs) + next E frag
            wh = *(const u32x4*)&whi[(long)wcol * KPAD + (c + 1) * 32 + wseg * 8];
            wl = *(const u32x4*)&wlo[(long)wcol * KPAD + (c + 1) * 32 + wseg * 8];
            long eo = erow * EMBD + (c + 1) * 32 + kgrp * 8;
            if (eo > EMAX) eo = EMAX;
            n0 = *(const f32x4*)&emb[eo];
            n1 = *(const f32x4*)&emb[eo + 4];
        }
        // convert current E to bf16 hi/lo fragments
        union { bf16x8 v; u32x4 u; } ehi, elo;
        {
            float ef[8] = {e0.x, e0.y, e0.z, e0.w, e1.x, e1.y, e1.z, e1.w};
            if (c == NCH - 1) {   // zero K-padding (avoid NaN*0)
#pragma unroll
                for (int j = 0; j < 8; ++j)
                    if (288 + kgrp * 8 + j >= EMBD) ef[j] = 0.f;
            }
            unsigned int hw[8], lw[8];
#pragma unroll
            for (int j = 0; j < 8; ++j) {
                unsigned int u = __float_as_uint(ef[j]);
                hw[j] = u >> 16;
                float r = __uint_as_float(u & 0xffff0000u);
                lw[j] = __float_as_uint(ef[j] - r) >> 16;
            }
            ehi.u = (u32x4){hw[0] | (hw[1] << 16), hw[2] | (hw[3] << 16),
                            hw[4] | (hw[5] << 16), hw[6] | (hw[7] << 16)};
            elo.u = (u32x4){lw[0] | (lw[1] << 16), lw[2] | (lw[3] << 16),
                            lw[4] | (lw[5] << 16), lw[6] | (lw[7] << 16)};
        }
#pragma unroll
        for (int t = 0; t < 8; ++t) {
            union { bf16x8 v; u32x4 u; } bh, bl;
            int a = (t * 16 + lrow) * WSTRIDE + kgrp * 8;
            bh.u = *(const u32x4*)&WtH[cur][a];
            bl.u = *(const u32x4*)&WtL[cur][a];
            acc[t] = __builtin_amdgcn_mfma_f32_16x16x32_bf16(ehi.v, bh.v, acc[t], 0, 0, 0);
            acc[t] = __builtin_amdgcn_mfma_f32_16x16x32_bf16(ehi.v, bl.v, acc[t], 0, 0, 0);
            acc[t] = __builtin_amdgcn_mfma_f32_16x16x32_bf16(elo.v, bh.v, acc[t], 0, 0, 0);
        }
        if (more) {
            *(u32x4*)&WtH[cur ^ 1][wcol * WSTRIDE + wseg * 8] = wh;
            *(u32x4*)&WtL[cur ^ 1][wcol * WSTRIDE + wseg * 8] = wl;
            e0 = n0; e1 = n1;
        }
        __syncthreads();
    }

    // epilogue: relu + W2 dot + 16-lane reduce + sigmoid*count
    const float b2 = sb2[0];
    float p[4];
#pragma unroll
    for (int i = 0; i < 4; ++i) {
        float s = 0.f;
#pragma unroll
        for (int t = 0; t < 8; ++t) {
            int col = t * 16 + lrow;
            float h = acc[t][i] + qcb_s[col];
            h = fmaxf(h, 0.f);
            s += h * w2_s[col];
        }
        s += __shfl_xor(s, 1); s += __shfl_xor(s, 2);
        s += __shfl_xor(s, 4); s += __shfl_xor(s, 8);
        p[i] = s;
    }
    if (lrow == 0) {
#pragma unroll
        for (int i = 0; i < 4; ++i) {
            int row = wave * 16 + kgrp * 4 + i;
            float wgt = -1.f;
            if (base + row < ncand)
                wgt = (float)ccn[row] / (1.f + expf(-(p[i] + b2)));
            wv[row] = wgt;
        }
    }
    __syncthreads();

    // wave 0: top-10 over the 128 row weights (2 per lane)
    if (tid < 64) {
        float w0 = wv[tid], w1 = wv[tid + 64];
        int i0 = (base + tid < ncand) ? cid[tid] : 0x7fffffff;
        int i1 = (base + tid + 64 < ncand) ? cid[tid + 64] : 0x7fffffff;
        for (int r = 0; r < NTOP; ++r) {
            float bw; int bid;
            if (w0 > w1 || (w0 == w1 && i0 < i1)) { bw = w0; bid = i0; }
            else                                   { bw = w1; bid = i1; }
            for (int m = 1; m < 64; m <<= 1) {
                float ow = __shfl_xor(bw, m); int oid = __shfl_xor(bid, m);
                if (ow > bw || (ow == bw && oid < bid)) { bw = ow; bid = oid; }
            }
            if (w0 == bw && i0 == bid)      w0 = -2.f;
            else if (w1 == bw && i1 == bid) w1 = -2.f;
            if (tid == r) { taw[blk * NTOP + r] = bw; tai[blk * NTOP + r] = bid; }
        }
    }
}

// ---------------- top-k helpers ----------------
__device__ __forceinline__ bool tbetter(float w1, int i1, float w2, int i2) {
    return w1 > w2 || (w1 == w2 && i1 < i2);
}

__device__ __forceinline__ void lds_insert(float* mw, int* mid, int t, float w, int id) {
    const int b = t * NTOP;
    if (!tbetter(w, id, mw[b + NTOP - 1], mid[b + NTOP - 1])) return;
    int p = NTOP - 1;
    while (p > 0 && tbetter(w, id, mw[b + p - 1], mid[b + p - 1])) {
        mw[b + p] = mw[b + p - 1]; mid[b + p] = mid[b + p - 1]; --p;
    }
    mw[b + p] = w; mid[b + p] = id;
}

// ---------------- final: global top-10 merge + expansion MLP ----------------
__global__ __launch_bounds__(512) void k_final(const float* __restrict__ taw,
                                               const int* __restrict__ tai,
                                               const float* __restrict__ qctx,
                                               const float* __restrict__ emb,
                                               const float* __restrict__ eW1,
                                               const float* __restrict__ eb1,
                                               const float* __restrict__ eW2,
                                               const float* __restrict__ eb2,
                                               float* __restrict__ out) {
    __shared__ float mw[512 * NTOP];   // 20 KB
    __shared__ int   mid[512 * NTOP];  // 20 KB
    __shared__ int   top_id[NTOP];
    __shared__ float qc[EMBD], em[EMBD], hbuf[HID];
    int t = threadIdx.x;
#pragma unroll
    for (int n = 0; n < NTOP; ++n) { mw[t * NTOP + n] = -1.f; mid[t * NTOP + n] = 0x7fffffff; }
    for (int i = t; i < SC_NBLK * NTOP; i += 512)
        lds_insert(mw, mid, t, taw[i], tai[i]);

    for (int s = 256; s > 0; s >>= 1) {
        __syncthreads();
        if (t < s) {
            const int ta = t * NTOP, tb = (t + s) * NTOP;
            float ow[NTOP]; int oid[NTOP];
            int i = 0, j = 0;
#pragma unroll
            for (int n = 0; n < NTOP; ++n) {
                float wa = mw[ta + i]; int ia = mid[ta + i];
                float wb = mw[tb + j]; int ib = mid[tb + j];
                if (tbetter(wa, ia, wb, ib)) { ow[n] = wa; oid[n] = ia; ++i; }
                else                         { ow[n] = wb; oid[n] = ib; ++j; }
            }
#pragma unroll
            for (int n = 0; n < NTOP; ++n) { mw[ta + n] = ow[n]; mid[ta + n] = oid[n]; }
        }
    }
    __syncthreads();

    if (t < NTOP) {
        top_id[t] = mid[t];
        out[EMBD + t] = (float)mid[t];
        out[EMBD + NTOP + t] = mw[t];
    }
    __syncthreads();

    for (int i = t; i < EMBD; i += 512) {
        float s = 0.f;
        for (int n = 0; n < NTOP; ++n) s += emb[(long)top_id[n] * EMBD + i];
        em[i] = s * (1.0f / NTOP);
        qc[i] = qctx[i];
    }
    __syncthreads();

    // h = relu(feat . eW1 + eb1); 4 threads per col, K split 75
    {
        int col = t >> 2, ks = t & 3;
        float a = 0.f;
        int k0 = ks * 75, k1 = k0 + 75;
        for (int k = k0; k < k1; ++k) {
            float q = qc[k], e = em[k];
            a += q * eW1[(long)k * HID + col];
            a += e * eW1[(long)(EMBD + k) * HID + col];
            a += (q * e) * eW1[(long)(2 * EMBD + k) * HID + col];
        }
        a += __shfl_xor(a, 1);
        a += __shfl_xor(a, 2);
        if (ks == 0) hbuf[col] = fmaxf(a + eb1[col], 0.f);
    }
    __syncthreads();

    for (int i = t; i < EMBD; i += 512) {
        float a = eb2[i];
        for (int j = 0; j < HID; ++j) a += hbuf[j] * eW2[(long)j * EMBD + i];
        out[i] = a;
    }
}

extern "C" void kernel_launch(void* const* d_in, const int* in_sizes, int n_in,
                              void* d_out, int out_size, void* d_ws, size_t ws_size,
                              hipStream_t stream) {
    const int* qterms  = (const int*)d_in[0];
    const int* fdocs   = (const int*)d_in[1];
    const float* emb   = (const float*)d_in[3];
    const float* sW1   = (const float*)d_in[4];
    const float* sb1   = (const float*)d_in[5];
    const float* sW2   = (const float*)d_in[6];
    const float* sb2   = (const float*)d_in[7];
    const float* eW1   = (const float*)d_in[8];
    const float* eb1   = (const float*)d_in[9];
    const float* eW2   = (const float*)d_in[10];
    const float* eb2   = (const float*)d_in[11];
    float* out = (float*)d_out;

    char* ws = (char*)d_ws;
    int*   counts = (int*)ws;                             // 400000
    int*   ncand  = (int*)(ws + 400000);                  // 4 (zeroed with counts)
    float* qctx   = (float*)(ws + 400064);                // 1200
    float* qcb    = (float*)(ws + 401280);                // 512
    float* taw    = (float*)(ws + 401792);                // 782*10*4 = 31280
    int*   tai    = (int*)(ws + 433088);                  // 31280
    unsigned short* whi = (unsigned short*)(ws + 464384); // 128*320*2 = 81920
    unsigned short* wlo = (unsigned short*)(ws + 546304); // 81920
    int* cand = nullptr; int* ccnt = nullptr;
    const bool use_compact = ws_size >= 1428224;
    if (use_compact) {
        cand = (int*)(ws + 628224);                       // 400000
        ccnt = (int*)(ws + 1028224);                      // 400000
    }

    int nflat = in_sizes[1];
    int hblocks = (nflat + 255) / 256;
    int wtblocks = (HID * KPAD + 255) / 256;              // 160
    int cblocks = (VOCABN + 255) / 256;                   // 391

    hipMemsetAsync(ws, 0, 400064, stream);                // counts + ncand
    k_pre<<<hblocks + 1 + wtblocks, 256, 0, stream>>>(qterms, fdocs, nflat, hblocks,
                                                      emb, sW1, counts, qctx, whi, wlo);
    k_compact<<<cblocks + 1, 256, 0, stream>>>(counts, cand, ccnt, ncand, cblocks,
                                               qctx, sW1, sb1, qcb);
    k_score<<<SC_NBLK, 512, 0, stream>>>(emb, whi, wlo, qcb, sW2, sb2,
                                         counts, cand, ccnt, ncand, taw, tai);
    k_final<<<1, 512, 0, stream>>>(taw, tai, qctx, emb, eW1, eb1, eW2, eb2, out);
}